// Round 5
// baseline (686.997 us; speedup 1.0000x reference)
//
#include <hip/hip_runtime.h>
#include <cstddef>
#include <cstdint>

#define DIN 64
#define HID 128
#define NBKMAX 256   // max dst buckets of 512 nodes -> supports N <= 131072
#define EPB 2048     // edges per bin-pass block

typedef _Float16 half4v __attribute__((ext_vector_type(4)));
typedef _Float16 half8v __attribute__((ext_vector_type(8)));
typedef float f32x16 __attribute__((ext_vector_type(16)));

// ---- order-preserving float<->uint for atomicMax-based segment max ----
__device__ __forceinline__ unsigned encf(float f) {
    unsigned b = __float_as_uint(f);
    return (b & 0x80000000u) ? ~b : (b | 0x80000000u);
}
__device__ __forceinline__ float decf(unsigned u) {
    unsigned b = (u & 0x80000000u) ? (u & 0x7FFFFFFFu) : ~u;
    return __uint_as_float(b);
}

// ---- fp32 -> f16 for both inputs in one launch ----
__global__ void conv_x2_k(const float* s0, _Float16* d0, int n40,
                          const float* s1, _Float16* d1, int n41) {
    int r = blockIdx.y;
    const float* s = r == 0 ? s0 : s1;
    _Float16* d = r == 0 ? d0 : d1;
    int n4 = r == 0 ? n40 : n41;
    int i = blockIdx.x * 256 + threadIdx.x;
    if (i >= n4) return;
    float4 v = *reinterpret_cast<const float4*>(&s[i * 4]);
    half4v h;
    h.x = (_Float16)v.x; h.y = (_Float16)v.y; h.z = (_Float16)v.z; h.w = (_Float16)v.w;
    *reinterpret_cast<half4v*>(&d[i * 4]) = h;
}

// ---- prep mega-kernel: 8 weight convert(+add)+transpose jobs (y=0..7),
//      bucket histogram x3 relations (y=8..10), segment bounds (y=11) ----
struct CW { const float* src; const float* src2; _Float16* dst; int K; int total; };
__global__ __launch_bounds__(256) void prep_k(
    CW c0, CW c1, CW c2, CW c3, CW c4, CW c5, CW c6, CW c7,
    const int* e0, const int* e1, const int* e2, int E,
    int* hc0, int* hc1, int* hc2,
    const int* bpe, int npe, int* spe,
    const int* brr, int nrr, int* srr, int G) {
    int y = blockIdx.y;
    if (y < 8) {
        CW J;
        switch (y) {
            case 0: J = c0; break; case 1: J = c1; break; case 2: J = c2; break;
            case 3: J = c3; break; case 4: J = c4; break; case 5: J = c5; break;
            case 6: J = c6; break; default: J = c7; break;
        }
        int i = blockIdx.x * 256 + threadIdx.x;
        if (i >= J.total) return;
        int m = i / (J.K * HID);
        int rem = i % (J.K * HID);
        int k = rem / HID;
        int col = rem % HID;
        float v = J.src[i];
        if (J.src2) v += J.src2[i];
        J.dst[(size_t)m * HID * J.K + (size_t)col * J.K + k] = (_Float16)v;
    } else if (y < 11) {
        int r = y - 8;
        const int* ei = r == 0 ? e0 : (r == 1 ? e1 : e2);
        int* cnt = r == 0 ? hc0 : (r == 1 ? hc1 : hc2);
        __shared__ int sc[NBKMAX];
        int t = threadIdx.x;
        sc[t] = 0;
        __syncthreads();
        int base = blockIdx.x * EPB;
        if (base >= E) return;
        int n = min(EPB, E - base);
        for (int i = t; i < n; i += 256)
            atomicAdd(&sc[(unsigned)ei[E + base + i] >> 9], 1);
        __syncthreads();
        if (sc[t]) atomicAdd(&cnt[t], sc[t]);
    } else {
        int r = blockIdx.x;
        if (r >= 2) return;
        const int* batch = r == 0 ? bpe : brr;
        int n = r == 0 ? npe : nrr;
        int* starts = r == 0 ? spe : srr;
        int g = threadIdx.x;
        if (g > G) return;
        int lo = 0, hi = n;
        while (lo < hi) {
            int mid = (lo + hi) >> 1;
            if (batch[mid] < g) lo = mid + 1; else hi = mid;
        }
        starts[g] = lo;
    }
}

// ================= CSR build via cache-local counting sort =================
__global__ __launch_bounds__(256) void bscan_k(int* c0, int* bb0, int* cu0, int* rp0, int n0,
                                               int* c1, int* bb1, int* cu1, int* rp1, int n1,
                                               int* c2, int* bb2, int* cu2, int* rp2, int n2,
                                               int E) {
    __shared__ int sh[256];
    int t = threadIdx.x;
    for (int r = 0; r < 3; ++r) {
        int* cnt = r == 0 ? c0 : (r == 1 ? c1 : c2);
        int* bb  = r == 0 ? bb0 : (r == 1 ? bb1 : bb2);
        int* cu  = r == 0 ? cu0 : (r == 1 ? cu1 : cu2);
        int* rp  = r == 0 ? rp0 : (r == 1 ? rp1 : rp2);
        int N    = r == 0 ? n0 : (r == 1 ? n1 : n2);
        int v = cnt[t];
        sh[t] = v;
        __syncthreads();
        for (int off = 1; off < 256; off <<= 1) {
            int val = (t >= off) ? sh[t - off] : 0;
            __syncthreads();
            sh[t] += val;
            __syncthreads();
        }
        int ex = sh[t] - v;
        bb[t] = ex;
        cu[t] = ex;
        if (t == 255) bb[256] = sh[255];
        if (t == 0) rp[N] = E;
        __syncthreads();
    }
}

__global__ __launch_bounds__(256) void bin_k(const int* e0, const int* e1, const int* e2, int E,
                                             int* cu0, int* cu1, int* cu2,
                                             unsigned* t0, unsigned* t1, unsigned* t2) {
    int r = blockIdx.y;
    const int* ei = r == 0 ? e0 : (r == 1 ? e1 : e2);
    int* gcur = r == 0 ? cu0 : (r == 1 ? cu1 : cu2);
    unsigned* temp = r == 0 ? t0 : (r == 1 ? t1 : t2);
    __shared__ unsigned pk[EPB];
    __shared__ unsigned short bkb[EPB];
    __shared__ int cnt[NBKMAX];
    __shared__ int scn[NBKMAX];
    __shared__ int rb[NBKMAX];
    int t = threadIdx.x;
    int base = blockIdx.x * EPB;
    int n = min(EPB, E - base);
    cnt[t] = 0;
    __syncthreads();
    for (int i = t; i < n; i += 256)
        atomicAdd(&cnt[(unsigned)ei[E + base + i] >> 9], 1);
    __syncthreads();
    {
        int v = cnt[t];
        scn[t] = v;
        __syncthreads();
        for (int off = 1; off < 256; off <<= 1) {
            int val = (t >= off) ? scn[t - off] : 0;
            __syncthreads();
            scn[t] += val;
            __syncthreads();
        }
        int ex = scn[t] - v;
        __syncthreads();
        scn[t] = ex;
    }
    {
        int c = cnt[t];
        rb[t] = c ? atomicAdd(&gcur[t], c) : 0;
        cnt[t] = 0;
    }
    __syncthreads();
    for (int i = t; i < n; i += 256) {
        int s = ei[base + i];
        int d = ei[E + base + i];
        int b = (unsigned)d >> 9;
        int slot = scn[b] + atomicAdd(&cnt[b], 1);
        pk[slot] = ((unsigned)s << 9) | (unsigned)(d & 511);
        bkb[slot] = (unsigned short)b;
    }
    __syncthreads();
    for (int i = t; i < n; i += 256) {
        int b = bkb[i];
        temp[rb[b] + (i - scn[b])] = pk[i];
    }
}

__global__ __launch_bounds__(256) void bcsr_k(const unsigned* t0, const unsigned* t1, const unsigned* t2,
                                              const int* bb0, const int* bb1, const int* bb2,
                                              int* rp0, int* rp1, int* rp2,
                                              int* a0, int* a1, int* a2,
                                              int n0, int n1, int n2) {
    int r = blockIdx.y;
    const unsigned* temp = r == 0 ? t0 : (r == 1 ? t1 : t2);
    const int* bb = r == 0 ? bb0 : (r == 1 ? bb1 : bb2);
    int* rp = r == 0 ? rp0 : (r == 1 ? rp1 : rp2);
    int* adj = r == 0 ? a0 : (r == 1 ? a1 : a2);
    int N = r == 0 ? n0 : (r == 1 ? n1 : n2);
    int b = blockIdx.x;
    int lo = bb[b], hi = bb[b + 1];
    __shared__ int cnt[512];
    __shared__ int sh[256];
    int t = threadIdx.x;
    cnt[t] = 0; cnt[t + 256] = 0;
    __syncthreads();
    for (int i = lo + t; i < hi; i += 256)
        atomicAdd(&cnt[temp[i] & 511], 1);
    __syncthreads();
    int c0 = cnt[2 * t], c1 = cnt[2 * t + 1];
    sh[t] = c0 + c1;
    __syncthreads();
    for (int off = 1; off < 256; off <<= 1) {
        int v = (t >= off) ? sh[t - off] : 0;
        __syncthreads();
        sh[t] += v;
        __syncthreads();
    }
    int pairExcl = sh[t] - (c0 + c1);
    __syncthreads();
    int e0x = lo + pairExcl;
    int e1x = e0x + c0;
    cnt[2 * t] = e0x;
    cnt[2 * t + 1] = e1x;
    int nodeBase = b * 512;
    if (nodeBase + 2 * t < N) rp[nodeBase + 2 * t] = e0x;
    if (nodeBase + 2 * t + 1 < N) rp[nodeBase + 2 * t + 1] = e1x;
    __syncthreads();
    for (int i = lo + t; i < hi; i += 256) {
        unsigned p = temp[i];
        int pos = atomicAdd(&cnt[p & 511], 1);
        adj[pos] = p >> 9;
    }
}

// ============ fused aggregate+GEMM, dual-job, 256 threads ============
// R4: the gather is fused into the GEMM.  Each A-source is either AGG
// (adj != null): block aggregates its 128 rows with the R1-proven CSR-walk
// directly into the granule-swizzled LDS A-tile (f32 regs -> f16 ds_write);
// or ROOT: global_load_lds with swizzle folded into the per-lane source addr.
// W staging/dbuf/barrier schedule identical to the proven R0 kernel.
// Eliminates the 75 MB AGG write + 75 MB A re-read per layer.
struct GJob {
    const _Float16* X0; const int* rp0; const int* adj0;   // src0: always AGG
    const _Float16* X1; const int* rp1; const int* adj1;   // src1: AGG, or ROOT if adj1==null
    const _Float16* X2;                                    // src2: ROOT (unused if nsrc==2)
    const _Float16* W0; const _Float16* W1; const _Float16* W2;
    const float* b0; const float* b1;
    _Float16* O;
    int N; int nsrc; int gb;
    const int* batch;           // SEGMAX only
    const int* starts;          // SEGMAX only
    unsigned* gmU;              // SEGMAX only (fallback sink)
    float* part;                // SEGMAX only: [gb][2][HID]
    int* pgid;                  // SEGMAX only: [gb][2]
};

template <bool RELU, bool SEGMAX, int K>
__global__ __launch_bounds__(256) void gemm2_k(GJob j0, GJob j1) {
    constexpr int CH = K / 64;       // K-chunks per source
    constexpr int TPN = K / 8;       // lanes per node row in agg
    constexpr int GRP = 256 / TPN;   // node rows aggregated per pass
    const bool second = ((int)blockIdx.x >= j0.gb);
    const GJob J = second ? j1 : j0;
    const int bx = blockIdx.x - (second ? j0.gb : 0);
    __shared__ _Float16 Alds[128 * K];       // 16/32 KB unified A tile
    __shared__ _Float16 Wlds[2][128 * 64];   // 2 x 16 KB
    const int tid = threadIdx.x;
    const int lane = tid & 63;
    const int w = tid >> 6;
    const int wr = w & 1, wc = w >> 1;
    const int rowBase = bx * 128;

    f32x16 acc[2][2];
#pragma unroll
    for (int r = 0; r < 2; ++r)
#pragma unroll
        for (int c = 0; c < 2; ++c)
#pragma unroll
            for (int q = 0; q < 16; ++q) acc[r][c][q] = 0.0f;

    const _Float16* Wp[3] = {J.W0, J.W1, J.W2};

    int srow[4], soff[4], ldsoff[4];
#pragma unroll
    for (int i = 0; i < 4; ++i) {
        int r_ = (w * 4 + i) * 8 + (lane >> 3);
        srow[i] = r_;
        soff[i] = ((lane & 7) ^ (r_ & 7)) << 4;
        ldsoff[i] = (w * 4 + i) << 10;
    }

    const int total = J.nsrc * CH;

    auto stageW = [&](int c_, int buf) {
        const int s_ = c_ / CH;
        const int k0b = (c_ - s_ * CH) << 7;
        const char* Wb = (const char*)Wp[s_];
        char* wl = (char*)&Wlds[buf][0];
#pragma unroll
        for (int i = 0; i < 4; ++i) {
            const char* gw = Wb + ((size_t)srow[i] * K) * 2 + k0b + soff[i];
            __builtin_amdgcn_global_load_lds(
                (const __attribute__((address_space(1))) void*)gw,
                (__attribute__((address_space(3))) void*)(wl + ldsoff[i]), 16, 0, 0);
        }
    };

    auto aggregate = [&](const _Float16* Xs, const int* rp, const int* adj) {
        const int gg = tid / TPN;
        const int glane = tid % TPN;
#pragma unroll 1
        for (int pass = 0; pass < 128 / GRP; ++pass) {
            const int lrow = pass * GRP + gg;
            const int node = rowBase + lrow;
            float a8[8] = {0.f, 0.f, 0.f, 0.f, 0.f, 0.f, 0.f, 0.f};
            if (node < J.N) {
                int a = rp[node], e1 = rp[node + 1];
                for (int base = a; base < e1; base += TPN) {
                    int idx = base + glane;
                    int myAdj = (idx < e1) ? adj[idx] : 0;
                    int cnt = min(TPN, e1 - base);
                    int j = 0;
                    for (; j + 4 <= cnt; j += 4) {
                        int s0 = __shfl(myAdj, j, TPN);
                        int s1 = __shfl(myAdj, j + 1, TPN);
                        int s2 = __shfl(myAdj, j + 2, TPN);
                        int s3 = __shfl(myAdj, j + 3, TPN);
                        half8v v0 = *reinterpret_cast<const half8v*>(&Xs[(size_t)s0 * K + glane * 8]);
                        half8v v1 = *reinterpret_cast<const half8v*>(&Xs[(size_t)s1 * K + glane * 8]);
                        half8v v2 = *reinterpret_cast<const half8v*>(&Xs[(size_t)s2 * K + glane * 8]);
                        half8v v3 = *reinterpret_cast<const half8v*>(&Xs[(size_t)s3 * K + glane * 8]);
#pragma unroll
                        for (int i = 0; i < 8; ++i)
                            a8[i] += (float)v0[i] + (float)v1[i] + (float)v2[i] + (float)v3[i];
                    }
                    for (; j < cnt; ++j) {
                        int s0 = __shfl(myAdj, j, TPN);
                        half8v v0 = *reinterpret_cast<const half8v*>(&Xs[(size_t)s0 * K + glane * 8]);
#pragma unroll
                        for (int i = 0; i < 8; ++i) a8[i] += (float)v0[i];
                    }
                }
            }
            half8v o;
#pragma unroll
            for (int i = 0; i < 8; ++i) o[i] = (_Float16)a8[i];
            int gran;
            if constexpr (K == 128)
                gran = lrow * 16 + (glane & 8) + ((glane & 7) ^ (lrow & 7));
            else
                gran = lrow * 8 + (glane ^ (lrow & 7));
            *reinterpret_cast<half8v*>(&Alds[gran * 8]) = o;
        }
    };

    auto stageRoot = [&](const _Float16* Xr) {
        char* al = (char*)&Alds[0];
        const char* Xb = (const char*)Xr;
        if constexpr (K == 128) {
#pragma unroll
            for (int i = 0; i < 8; ++i) {
                int rr = w * 32 + i * 4 + (lane >> 4);
                int g16 = lane & 15;
                int sb = (g16 & 8) * 16 + (((g16 & 7) ^ (rr & 7)) << 4);
                __builtin_amdgcn_global_load_lds(
                    (const __attribute__((address_space(1))) void*)(Xb + (size_t)(rowBase + rr) * 256 + sb),
                    (__attribute__((address_space(3))) void*)(al + (w * 32 + i * 4) * 256 + lane * 16), 16, 0, 0);
            }
        } else {
#pragma unroll
            for (int i = 0; i < 4; ++i) {
                int rr = w * 32 + i * 8 + (lane >> 3);
                int g8 = lane & 7;
                int sb = (g8 ^ (rr & 7)) << 4;
                __builtin_amdgcn_global_load_lds(
                    (const __attribute__((address_space(1))) void*)(Xb + (size_t)(rowBase + rr) * 128 + sb),
                    (__attribute__((address_space(3))) void*)(al + (w * 32 + i * 8) * 128 + lane * 16), 16, 0, 0);
            }
        }
    };

    const int rA0 = wr * 64 + (lane & 31);
    const int cW0 = wc * 64 + (lane & 31);
    const int ghi = lane >> 5;

    int c = 0;
    for (int s = 0; s < J.nsrc; ++s) {
        const _Float16* Xs = s == 0 ? J.X0 : (s == 1 ? J.X1 : J.X2);
        const int* rpS = s == 0 ? J.rp0 : (s == 1 ? J.rp1 : nullptr);
        const int* adjS = s == 0 ? J.adj0 : (s == 1 ? J.adj1 : nullptr);
        if (adjS != nullptr) {
            aggregate(Xs, rpS, adjS);
            if (c == 0) stageW(0, 0);
            __syncthreads();
        } else {
            stageRoot(Xs);
            asm volatile("s_waitcnt vmcnt(0)\n\ts_barrier" ::: "memory");
        }
        for (int kc = 0; kc < CH; ++kc, ++c) {
            if (c + 1 < total) stageW(c + 1, (c + 1) & 1);
            const _Float16* wl = &Wlds[c & 1][0];
#pragma unroll
            for (int t = 0; t < 4; ++t) {
                const int g = 2 * t + ghi;
                half8v av[2], wv[2];
#pragma unroll
                for (int r = 0; r < 2; ++r) {
                    const int row = rA0 + r * 32;
                    av[r] = *reinterpret_cast<const half8v*>(&Alds[(row * TPN + kc * 8 + (g ^ (row & 7))) * 8]);
                }
#pragma unroll
                for (int cc = 0; cc < 2; ++cc) {
                    const int col = cW0 + cc * 32;
                    wv[cc] = *reinterpret_cast<const half8v*>(&wl[(col * 8 + (g ^ (col & 7))) * 8]);
                }
#pragma unroll
                for (int r = 0; r < 2; ++r)
#pragma unroll
                    for (int cc = 0; cc < 2; ++cc)
                        acc[r][cc] = __builtin_amdgcn_mfma_f32_32x32x16_f16(wv[cc], av[r], acc[r][cc], 0, 0, 0);
            }
            asm volatile("s_waitcnt vmcnt(0)\n\ts_barrier" ::: "memory");
        }
    }

    const int half_ = lane >> 5;   // lanes l and l^32 own the same node
    const int lane31 = lane & 31;

    if constexpr (SEGMAX) {
        __shared__ float smaxS[2][2][HID];   // [slot][wr][f]
        const float NEGINF = -__builtin_huge_valf();
        {
            float* sf = (float*)smaxS;
            sf[tid] = NEGINF;
            sf[tid + 256] = NEGINF;
        }
        const int node0 = rowBase + wr * 64 + lane31;
        const int node1 = node0 + 32;
        const bool ok0 = (node0 < J.N);
        const bool ok1 = (node1 < J.N);
        const int lastn = min(rowBase + 127, J.N - 1);
        const int gfirst = J.batch[rowBase];
        const int glast = J.batch[lastn];
        const int gcnt = glast - gfirst + 1;
        __syncthreads();
        if (gcnt <= 2) {
            const int boundary = (gcnt == 2) ? J.starts[gfirst + 1] : 0x7FFFFFFF;
            for (int s = 0; s < gcnt; ++s) {
                const bool in0 = ok0 && ((node0 >= boundary) == (s == 1));
                const bool in1 = ok1 && ((node1 >= boundary) == (s == 1));
#pragma unroll
                for (int cc = 0; cc < 2; ++cc)
#pragma unroll
                for (int g = 0; g < 4; ++g) {
                    const int f = wc * 64 + cc * 32 + g * 8 + 4 * half_;
                    float4 bv = *reinterpret_cast<const float4*>(&J.b0[f]);
                    if (J.b1) {
                        float4 b2v = *reinterpret_cast<const float4*>(&J.b1[f]);
                        bv.x += b2v.x; bv.y += b2v.y; bv.z += b2v.z; bv.w += b2v.w;
                    }
#pragma unroll
                    for (int i = 0; i < 4; ++i) {
                        float bb_ = ((const float*)&bv)[i];
                        float v0 = in0 ? (acc[0][cc][g * 4 + i] + bb_) : NEGINF;
                        float v1 = in1 ? (acc[1][cc][g * 4 + i] + bb_) : NEGINF;
                        float vm = fmaxf(v0, v1);
#pragma unroll
                        for (int off = 1; off < 32; off <<= 1)
                            vm = fmaxf(vm, __shfl_xor(vm, off, 32));
                        if (lane31 == 0) smaxS[s][wr][f + i] = vm;
                    }
                }
            }
        } else {
            // astronomically rare (>2 graphs in one 128-row block): direct atomics
#pragma unroll
            for (int r = 0; r < 2; ++r) {
                const int node = rowBase + wr * 64 + r * 32 + lane31;
                if (node >= J.N) continue;
                const int gid = J.batch[node];
                unsigned* gbase = J.gmU + (size_t)gid * HID;
#pragma unroll
                for (int cc = 0; cc < 2; ++cc)
#pragma unroll
                for (int g = 0; g < 4; ++g) {
                    const int f = wc * 64 + cc * 32 + g * 8 + 4 * half_;
                    float4 bv = *reinterpret_cast<const float4*>(&J.b0[f]);
                    if (J.b1) {
                        float4 b2v = *reinterpret_cast<const float4*>(&J.b1[f]);
                        bv.x += b2v.x; bv.y += b2v.y; bv.z += b2v.z; bv.w += b2v.w;
                    }
#pragma unroll
                    for (int i = 0; i < 4; ++i) {
                        float v = acc[r][cc][g * 4 + i] + ((const float*)&bv)[i];
                        atomicMax(&gbase[f + i], encf(v));
                    }
                }
            }
        }
        __syncthreads();
        if (tid < 128) {
#pragma unroll
            for (int s = 0; s < 2; ++s) {
                float m = fmaxf(smaxS[s][0][tid], smaxS[s][1][tid]);
                J.part[((size_t)bx * 2 + s) * HID + tid] = m;
            }
        }
        if (tid < 2) J.pgid[bx * 2 + tid] = (gcnt <= 2 && tid < gcnt) ? gfirst + tid : -1;
        return;
    }

    // ---- epilogue: lane-pair merged 16 B stores ----
#pragma unroll
    for (int r = 0; r < 2; ++r) {
        int node = rowBase + (wr * 2 + r) * 32 + lane31;
        bool ok = (node < J.N);
        _Float16* orow = J.O + (size_t)node * HID;
#pragma unroll
        for (int cc = 0; cc < 2; ++cc) {
            int fbase = wc * 64 + cc * 32;
#pragma unroll
            for (int g = 0; g < 4; ++g) {
                int fmine = fbase + g * 8 + 4 * half_;
                float4 bv = *reinterpret_cast<const float4*>(&J.b0[fmine]);
                if (J.b1) {
                    float4 b2v = *reinterpret_cast<const float4*>(&J.b1[fmine]);
                    bv.x += b2v.x; bv.y += b2v.y; bv.z += b2v.z; bv.w += b2v.w;
                }
                union { half4v h; int i[2]; } m, p;
#pragma unroll
                for (int i = 0; i < 4; ++i) {
                    float v = acc[r][cc][g * 4 + i] + ((const float*)&bv)[i];
                    if (RELU) v = fmaxf(v, 0.f);
                    m.h[i] = (_Float16)v;
                }
                p.i[0] = __shfl_xor(m.i[0], 32);
                p.i[1] = __shfl_xor(m.i[1], 32);
                half4v lo = half_ ? p.h : m.h;
                half4v hi = half_ ? m.h : p.h;
                half8v outv;
#pragma unroll
                for (int i = 0; i < 4; ++i) { outv[i] = lo[i]; outv[4 + i] = hi[i]; }
                if (ok && ((g & 1) == half_))
                    *reinterpret_cast<half8v*>(&orow[fbase + g * 8]) = outv;
            }
        }
    }
}

// ---- partial-max reduction: grid (G, 2), 128 threads ----
__global__ __launch_bounds__(128) void segred_k(
    const float* pP, const int* gP, const int* stP, unsigned* gmP,
    const float* pR, const int* gR, const int* stR, unsigned* gmR) {
    int z = blockIdx.y;
    const float* part = z == 0 ? pP : pR;
    const int* pgid   = z == 0 ? gP : gR;
    const int* starts = z == 0 ? stP : stR;
    unsigned* gmU     = z == 0 ? gmP : gmR;
    int g = blockIdx.x;
    int f = threadIdx.x;
    int s0 = starts[g], s1 = starts[g + 1];
    if (s0 >= s1) return;
    int b0 = s0 >> 7, b1 = (s1 - 1) >> 7;
    float m = -__builtin_huge_valf();
    for (int b = b0; b <= b1; ++b) {
#pragma unroll
        for (int s = 0; s < 2; ++s) {
            if (pgid[b * 2 + s] == g)
                m = fmaxf(m, part[((size_t)b * 2 + s) * HID + f]);
        }
    }
    atomicMax(&gmU[g * HID + f], encf(m));
}

// ---- per-graph MLP heads + final combine ----
__global__ void head_k(const unsigned* __restrict__ gmU_pe, const unsigned* __restrict__ gmU_r,
                       const float* __restrict__ W1, const float* __restrict__ b1,
                       const float* __restrict__ W2, const float* __restrict__ b2,
                       const float* __restrict__ oW, const float* __restrict__ ob,
                       float* __restrict__ out, int G) {
    int g = threadIdx.x;
    if (g >= G) return;
    float vals[2];
#pragma unroll
    for (int t = 0; t < 2; ++t) {
        const unsigned* gm = t ? gmU_r : gmU_pe;
        float z[5];
#pragma unroll
        for (int j = 0; j < 5; ++j) z[j] = b1[t * 5 + j];
        for (int f = 0; f < HID; ++f) {
            float x = decf(gm[g * HID + f]);
#pragma unroll
            for (int j = 0; j < 5; ++j) z[j] = fmaf(x, W1[t * HID * 5 + f * 5 + j], z[j]);
        }
        float o = b2[t];
#pragma unroll
        for (int j = 0; j < 5; ++j) o = fmaf(fmaxf(z[j], 0.f), W2[t * 5 + j], o);
        vals[t] = o;
    }
    out[g] = vals[0] * oW[0] + vals[1] * oW[1] + ob[0];
}

extern "C" void kernel_launch(void* const* d_in, const int* in_sizes, int n_in,
                              void* d_out, int out_size, void* d_ws, size_t ws_size,
                              hipStream_t stream) {
    const float* x_pe    = (const float*)d_in[0];
    const float* x_r     = (const float*)d_in[1];
    const int* ei_per    = (const int*)d_in[2];
    const int* ei_rpe    = (const int*)d_in[3];
    const int* ei_rr     = (const int*)d_in[4];
    const int* batch_pe  = (const int*)d_in[5];
    const int* batch_r   = (const int*)d_in[6];
    const float* Wrel1   = (const float*)d_in[7];
    const float* brel1   = (const float*)d_in[8];
    const float* Wroot1  = (const float*)d_in[9];
    const float* Wrel23  = (const float*)d_in[10];
    const float* brel23  = (const float*)d_in[11];
    const float* Wroot23 = (const float*)d_in[12];
    const float* mlp_W1  = (const float*)d_in[13];
    const float* mlp_b1  = (const float*)d_in[14];
    const float* mlp_W2  = (const float*)d_in[15];
    const float* mlp_b2  = (const float*)d_in[16];
    const float* out_W   = (const float*)d_in[17];
    const float* out_b   = (const float*)d_in[18];
    float* out = (float*)d_out;

    const int N_PE = in_sizes[0] / DIN;
    const int N_R  = in_sizes[1] / DIN;
    const int E    = in_sizes[2] / 2;
    const int G    = out_size;
    const int NMAX = (N_PE > N_R) ? N_PE : N_R;
    const size_t SZM = (size_t)NMAX * HID;

    // ---- workspace layout ----
    _Float16* H1 = (_Float16*)d_ws;
    _Float16* H2 = H1 + SZM;
    _Float16* H3 = H2 + SZM;
    _Float16* H4 = H3 + SZM;
    _Float16* H5 = H4 + SZM;
    _Float16* xh_pe = H5 + SZM;
    _Float16* xh_r  = xh_pe + (size_t)N_PE * DIN;
    _Float16* wt_rel1    = xh_r + (size_t)N_R * DIN;   // 3 x 128 x 64
    _Float16* wt_root1pe = wt_rel1 + 3 * DIN * HID;    // 128 x 64
    _Float16* wt_wsum1   = wt_root1pe + DIN * HID;     // 128 x 64
    _Float16* wt_rel23   = wt_wsum1 + DIN * HID;       // 6 x 128 x 128
    _Float16* wt_root_l2 = wt_rel23 + 6 * HID * HID;   // 128 x 128
    _Float16* wt_root_l3 = wt_root_l2 + HID * HID;     // 128 x 128
    _Float16* wt_wsum2   = wt_root_l3 + HID * HID;     // 128 x 128
    _Float16* wt_wsum3   = wt_wsum2 + HID * HID;       // 128 x 128
    unsigned* gmU_pe = (unsigned*)(wt_wsum3 + HID * HID);
    unsigned* gmU_r  = gmU_pe + G * HID;
    int* bktCnt = (int*)(gmU_r + G * HID);       // 3 * NBKMAX
    int* starts_pe = bktCnt + 3 * NBKMAX;
    int* starts_r  = starts_pe + (G + 1);
    int* bb     = starts_r + (G + 1);            // 3 * (NBKMAX+1)
    int* gcur   = bb + 3 * (NBKMAX + 1);         // 3 * NBKMAX
    int* csr    = gcur + 3 * NBKMAX;
    const size_t relstride = (size_t)(NMAX + 1) + 2 * (size_t)E + 16;

    int* rp[3]; int* adjp[3]; unsigned* tmp[3];
    const int Nds[3] = {N_R, N_PE, N_R};
    for (int r = 0; r < 3; ++r) {
        int* rowptr = csr + (size_t)r * relstride;
        rp[r] = rowptr;
        adjp[r] = rowptr + (Nds[r] + 1);
        tmp[r] = (unsigned*)(adjp[r] + E);
    }

    const int gpe = (N_PE + 127) / 128, grr = (N_R + 127) / 128;
    const int eb = (E + EPB - 1) / EPB;

    // ---- segmax partial buffers carved from tmp[0] scratch (free during layers) ----
    float* part_pe = (float*)tmp[0];
    float* part_r  = part_pe + (size_t)gpe * 2 * HID;
    int*   pgid_pe = (int*)(part_r + (size_t)grr * 2 * HID);
    int*   pgid_r  = pgid_pe + gpe * 2;

    // ---- zero gmU + bucket counters (contiguous) ----
    hipMemsetAsync(gmU_pe, 0, (2 * (size_t)G * HID + 3 * NBKMAX) * sizeof(int), stream);
    // ---- input conversion ----
    {
        int n40 = N_PE * DIN / 4, n41 = N_R * DIN / 4;
        int nmax = n40 > n41 ? n40 : n41;
        dim3 g((nmax + 255) / 256, 2);
        conv_x2_k<<<g, 256, 0, stream>>>(x_pe, xh_pe, n40, x_r, xh_r, n41);
    }
    // ---- prep: weight conversion + bucket hist + segment bounds, 1 launch ----
    {
        CW c0{Wrel1, nullptr, wt_rel1, DIN, 3 * DIN * HID};
        CW c1{Wroot1 + 1 * DIN * HID, nullptr, wt_root1pe, DIN, DIN * HID};
        CW c2{Wroot1, Wroot1 + 2 * DIN * HID, wt_wsum1, DIN, DIN * HID};
        CW c3{Wrel23, nullptr, wt_rel23, HID, 6 * HID * HID};
        CW c4{Wroot23 + 1 * HID * HID, nullptr, wt_root_l2, HID, HID * HID};
        CW c5{Wroot23 + 4 * HID * HID, nullptr, wt_root_l3, HID, HID * HID};
        CW c6{Wroot23, Wroot23 + 2 * HID * HID, wt_wsum2, HID, HID * HID};
        CW c7{Wroot23 + 3 * HID * HID, Wroot23 + 5 * HID * HID, wt_wsum3, HID, HID * HID};
        int gx = (6 * HID * HID + 255) / 256;
        if (eb > gx) gx = eb;
        dim3 g(gx, 12);
        prep_k<<<g, 256, 0, stream>>>(c0, c1, c2, c3, c4, c5, c6, c7,
                                      ei_per, ei_rpe, ei_rr, E,
                                      bktCnt, bktCnt + NBKMAX, bktCnt + 2 * NBKMAX,
                                      batch_pe, N_PE, starts_pe,
                                      batch_r, N_R, starts_r, G);
    }
    // ---- CSR build ----
    {
        bscan_k<<<1, 256, 0, stream>>>(
            bktCnt, bb, gcur, rp[0], Nds[0],
            bktCnt + NBKMAX, bb + (NBKMAX + 1), gcur + NBKMAX, rp[1], Nds[1],
            bktCnt + 2 * NBKMAX, bb + 2 * (NBKMAX + 1), gcur + 2 * NBKMAX, rp[2], Nds[2], E);
        dim3 gh(eb, 3);
        bin_k<<<gh, 256, 0, stream>>>(ei_per, ei_rpe, ei_rr, E,
                                      gcur, gcur + NBKMAX, gcur + 2 * NBKMAX,
                                      tmp[0], tmp[1], tmp[2]);
        dim3 gc(NBKMAX, 3);
        bcsr_k<<<gc, 256, 0, stream>>>(tmp[0], tmp[1], tmp[2],
                                       bb, bb + (NBKMAX + 1), bb + 2 * (NBKMAX + 1),
                                       rp[0], rp[1], rp[2],
                                       adjp[0], adjp[1], adjp[2],
                                       Nds[0], Nds[1], Nds[2]);
    }

    // ---------- layer 1 (K = 64), fused agg+gemm ----------
    {
        GJob jp{xh_r, rp[1], adjp[1],
                xh_pe, nullptr, nullptr,
                nullptr,
                wt_rel1 + 1 * DIN * HID, wt_root1pe, nullptr,
                brel1 + HID, nullptr, H4, N_PE, 2, gpe,
                nullptr, nullptr, nullptr, nullptr, nullptr};
        GJob jr{xh_pe, rp[0], adjp[0],
                xh_r, rp[2], adjp[2],
                xh_r,
                wt_rel1, wt_rel1 + 2 * DIN * HID, wt_wsum1,
                brel1, brel1 + 2 * HID, H5, N_R, 3, grr,
                nullptr, nullptr, nullptr, nullptr, nullptr};
        gemm2_k<true, false, 64><<<gpe + grr, 256, 0, stream>>>(jp, jr);
    }
    // ---------- layer 2 (K = 128), fused agg+gemm ----------
    {
        GJob jp{H5, rp[1], adjp[1],
                H4, nullptr, nullptr,
                nullptr,
                wt_rel23 + 1 * HID * HID, wt_root_l2, nullptr,
                brel23 + HID, nullptr, H1, N_PE, 2, gpe,
                nullptr, nullptr, nullptr, nullptr, nullptr};
        GJob jr{H4, rp[0], adjp[0],
                H5, rp[2], adjp[2],
                H5,
                wt_rel23, wt_rel23 + 2 * HID * HID, wt_wsum2,
                brel23, brel23 + 2 * HID, H2, N_R, 3, grr,
                nullptr, nullptr, nullptr, nullptr, nullptr};
        gemm2_k<true, false, 128><<<gpe + grr, 256, 0, stream>>>(jp, jr);
    }
    // ---------- layer 3 (K = 128), fused agg+gemm+segment-max ----------
    {
        GJob jp{H2, rp[1], adjp[1],
                H1, nullptr, nullptr,
                nullptr,
                wt_rel23 + 4 * HID * HID, wt_root_l3, nullptr,
                brel23 + 4 * HID, nullptr, nullptr, N_PE, 2, gpe,
                batch_pe, starts_pe, gmU_pe, part_pe, pgid_pe};
        GJob jr{H1, rp[0], adjp[0],
                H2, rp[2], adjp[2],
                H2,
                wt_rel23 + 3 * HID * HID, wt_rel23 + 5 * HID * HID, wt_wsum3,
                brel23 + 3 * HID, brel23 + 5 * HID, nullptr, N_R, 3, grr,
                batch_r, starts_r, gmU_r, part_r, pgid_r};
        gemm2_k<false, true, 128><<<gpe + grr, 256, 0, stream>>>(jp, jr);
    }

    // ---------- readout: partial reduce + heads ----------
    segred_k<<<dim3(G, 2), 128, 0, stream>>>(part_pe, pgid_pe, starts_pe, gmU_pe,
                                             part_r, pgid_r, starts_r, gmU_r);
    head_k<<<1, 64, 0, stream>>>(gmU_pe, gmU_r, mlp_W1, mlp_b1, mlp_W2, mlp_b2, out_W, out_b, out, G);
}

// Round 6
// 522.754 us; speedup vs baseline: 1.3142x; 1.3142x over previous
//
#include <hip/hip_runtime.h>
#include <cstddef>
#include <cstdint>

#define DIN 64
#define HID 128
#define NBKMAX 256   // max dst buckets of 512 nodes -> supports N <= 131072
#define EPB 2048     // edges per bin-pass block

typedef _Float16 half4v __attribute__((ext_vector_type(4)));
typedef _Float16 half8v __attribute__((ext_vector_type(8)));
typedef float f32x16 __attribute__((ext_vector_type(16)));

// ---- order-preserving float<->uint for atomicMax-based segment max ----
__device__ __forceinline__ unsigned encf(float f) {
    unsigned b = __float_as_uint(f);
    return (b & 0x80000000u) ? ~b : (b | 0x80000000u);
}
__device__ __forceinline__ float decf(unsigned u) {
    unsigned b = (u & 0x80000000u) ? (u & 0x7FFFFFFFu) : ~u;
    return __uint_as_float(b);
}

// ---- fp32 -> f16 for both inputs in one launch ----
__global__ void conv_x2_k(const float* s0, _Float16* d0, int n40,
                          const float* s1, _Float16* d1, int n41) {
    int r = blockIdx.y;
    const float* s = r == 0 ? s0 : s1;
    _Float16* d = r == 0 ? d0 : d1;
    int n4 = r == 0 ? n40 : n41;
    int i = blockIdx.x * 256 + threadIdx.x;
    if (i >= n4) return;
    float4 v = *reinterpret_cast<const float4*>(&s[i * 4]);
    half4v h;
    h.x = (_Float16)v.x; h.y = (_Float16)v.y; h.z = (_Float16)v.z; h.w = (_Float16)v.w;
    *reinterpret_cast<half4v*>(&d[i * 4]) = h;
}

// ---- prep mega-kernel: 8 weight convert(+add)+transpose jobs (y=0..7),
//      bucket histogram x3 relations (y=8..10), segment bounds (y=11) ----
struct CW { const float* src; const float* src2; _Float16* dst; int K; int total; };
__global__ __launch_bounds__(256) void prep_k(
    CW c0, CW c1, CW c2, CW c3, CW c4, CW c5, CW c6, CW c7,
    const int* e0, const int* e1, const int* e2, int E,
    int* hc0, int* hc1, int* hc2,
    const int* bpe, int npe, int* spe,
    const int* brr, int nrr, int* srr, int G) {
    int y = blockIdx.y;
    if (y < 8) {
        CW J;
        switch (y) {
            case 0: J = c0; break; case 1: J = c1; break; case 2: J = c2; break;
            case 3: J = c3; break; case 4: J = c4; break; case 5: J = c5; break;
            case 6: J = c6; break; default: J = c7; break;
        }
        int i = blockIdx.x * 256 + threadIdx.x;
        if (i >= J.total) return;
        int m = i / (J.K * HID);
        int rem = i % (J.K * HID);
        int k = rem / HID;
        int col = rem % HID;
        float v = J.src[i];
        if (J.src2) v += J.src2[i];
        J.dst[(size_t)m * HID * J.K + (size_t)col * J.K + k] = (_Float16)v;
    } else if (y < 11) {
        int r = y - 8;
        const int* ei = r == 0 ? e0 : (r == 1 ? e1 : e2);
        int* cnt = r == 0 ? hc0 : (r == 1 ? hc1 : hc2);
        __shared__ int sc[NBKMAX];
        int t = threadIdx.x;
        sc[t] = 0;
        __syncthreads();
        int base = blockIdx.x * EPB;
        if (base >= E) return;
        int n = min(EPB, E - base);
        for (int i = t; i < n; i += 256)
            atomicAdd(&sc[(unsigned)ei[E + base + i] >> 9], 1);
        __syncthreads();
        if (sc[t]) atomicAdd(&cnt[t], sc[t]);
    } else {
        int r = blockIdx.x;
        if (r >= 2) return;
        const int* batch = r == 0 ? bpe : brr;
        int n = r == 0 ? npe : nrr;
        int* starts = r == 0 ? spe : srr;
        int g = threadIdx.x;
        if (g > G) return;
        int lo = 0, hi = n;
        while (lo < hi) {
            int mid = (lo + hi) >> 1;
            if (batch[mid] < g) lo = mid + 1; else hi = mid;
        }
        starts[g] = lo;
    }
}

// ================= CSR build via cache-local counting sort =================
__global__ __launch_bounds__(256) void bscan_k(int* c0, int* bb0, int* cu0, int* rp0, int n0,
                                               int* c1, int* bb1, int* cu1, int* rp1, int n1,
                                               int* c2, int* bb2, int* cu2, int* rp2, int n2,
                                               int E) {
    __shared__ int sh[256];
    int t = threadIdx.x;
    for (int r = 0; r < 3; ++r) {
        int* cnt = r == 0 ? c0 : (r == 1 ? c1 : c2);
        int* bb  = r == 0 ? bb0 : (r == 1 ? bb1 : bb2);
        int* cu  = r == 0 ? cu0 : (r == 1 ? cu1 : cu2);
        int* rp  = r == 0 ? rp0 : (r == 1 ? rp1 : rp2);
        int N    = r == 0 ? n0 : (r == 1 ? n1 : n2);
        int v = cnt[t];
        sh[t] = v;
        __syncthreads();
        for (int off = 1; off < 256; off <<= 1) {
            int val = (t >= off) ? sh[t - off] : 0;
            __syncthreads();
            sh[t] += val;
            __syncthreads();
        }
        int ex = sh[t] - v;
        bb[t] = ex;
        cu[t] = ex;
        if (t == 255) bb[256] = sh[255];
        if (t == 0) rp[N] = E;
        __syncthreads();
    }
}

__global__ __launch_bounds__(256) void bin_k(const int* e0, const int* e1, const int* e2, int E,
                                             int* cu0, int* cu1, int* cu2,
                                             unsigned* t0, unsigned* t1, unsigned* t2) {
    int r = blockIdx.y;
    const int* ei = r == 0 ? e0 : (r == 1 ? e1 : e2);
    int* gcur = r == 0 ? cu0 : (r == 1 ? cu1 : cu2);
    unsigned* temp = r == 0 ? t0 : (r == 1 ? t1 : t2);
    __shared__ unsigned pk[EPB];
    __shared__ unsigned short bkb[EPB];
    __shared__ int cnt[NBKMAX];
    __shared__ int scn[NBKMAX];
    __shared__ int rb[NBKMAX];
    int t = threadIdx.x;
    int base = blockIdx.x * EPB;
    int n = min(EPB, E - base);
    cnt[t] = 0;
    __syncthreads();
    for (int i = t; i < n; i += 256)
        atomicAdd(&cnt[(unsigned)ei[E + base + i] >> 9], 1);
    __syncthreads();
    {
        int v = cnt[t];
        scn[t] = v;
        __syncthreads();
        for (int off = 1; off < 256; off <<= 1) {
            int val = (t >= off) ? scn[t - off] : 0;
            __syncthreads();
            scn[t] += val;
            __syncthreads();
        }
        int ex = scn[t] - v;
        __syncthreads();
        scn[t] = ex;
    }
    {
        int c = cnt[t];
        rb[t] = c ? atomicAdd(&gcur[t], c) : 0;
        cnt[t] = 0;
    }
    __syncthreads();
    for (int i = t; i < n; i += 256) {
        int s = ei[base + i];
        int d = ei[E + base + i];
        int b = (unsigned)d >> 9;
        int slot = scn[b] + atomicAdd(&cnt[b], 1);
        pk[slot] = ((unsigned)s << 9) | (unsigned)(d & 511);
        bkb[slot] = (unsigned short)b;
    }
    __syncthreads();
    for (int i = t; i < n; i += 256) {
        int b = bkb[i];
        temp[rb[b] + (i - scn[b])] = pk[i];
    }
}

__global__ __launch_bounds__(256) void bcsr_k(const unsigned* t0, const unsigned* t1, const unsigned* t2,
                                              const int* bb0, const int* bb1, const int* bb2,
                                              int* rp0, int* rp1, int* rp2,
                                              int* a0, int* a1, int* a2,
                                              int n0, int n1, int n2) {
    int r = blockIdx.y;
    const unsigned* temp = r == 0 ? t0 : (r == 1 ? t1 : t2);
    const int* bb = r == 0 ? bb0 : (r == 1 ? bb1 : bb2);
    int* rp = r == 0 ? rp0 : (r == 1 ? rp1 : rp2);
    int* adj = r == 0 ? a0 : (r == 1 ? a1 : a2);
    int N = r == 0 ? n0 : (r == 1 ? n1 : n2);
    int b = blockIdx.x;
    int lo = bb[b], hi = bb[b + 1];
    __shared__ int cnt[512];
    __shared__ int sh[256];
    int t = threadIdx.x;
    cnt[t] = 0; cnt[t + 256] = 0;
    __syncthreads();
    for (int i = lo + t; i < hi; i += 256)
        atomicAdd(&cnt[temp[i] & 511], 1);
    __syncthreads();
    int c0 = cnt[2 * t], c1 = cnt[2 * t + 1];
    sh[t] = c0 + c1;
    __syncthreads();
    for (int off = 1; off < 256; off <<= 1) {
        int v = (t >= off) ? sh[t - off] : 0;
        __syncthreads();
        sh[t] += v;
        __syncthreads();
    }
    int pairExcl = sh[t] - (c0 + c1);
    __syncthreads();
    int e0x = lo + pairExcl;
    int e1x = e0x + c0;
    cnt[2 * t] = e0x;
    cnt[2 * t + 1] = e1x;
    int nodeBase = b * 512;
    if (nodeBase + 2 * t < N) rp[nodeBase + 2 * t] = e0x;
    if (nodeBase + 2 * t + 1 < N) rp[nodeBase + 2 * t + 1] = e1x;
    __syncthreads();
    for (int i = lo + t; i < hi; i += 256) {
        unsigned p = temp[i];
        int pos = atomicAdd(&cnt[p & 511], 1);
        adj[pos] = p >> 9;
    }
}

// ---- 3 gather-sum aggregations in one launch (cooperative adj via shfl) ----
// R1-proven version (70 us @ 4.1 TB/s, 73% occupancy, BW-regime).  Fusing this
// into the GEMM (R4) or dual-node interleave (R1x) both regressed: the pattern
// needs MANY low-VGPR waves.  Do not fuse.
struct AJob { const _Float16* X; const int* rp; const int* adj; _Float16* AGG; int N; int gb; };
template <int D>
__global__ __launch_bounds__(256) void gather3_k(AJob a0, AJob a1, AJob a2) {
    int b = blockIdx.x;
    AJob J;
    if (b < a0.gb) { J = a0; }
    else if (b < a0.gb + a1.gb) { J = a1; b -= a0.gb; }
    else { J = a2; b -= a0.gb + a1.gb; }
    constexpr int TPN = D / 8;
    constexpr int NPB = 256 / TPN;
    int node = b * NPB + threadIdx.x / TPN;
    int glane = threadIdx.x % TPN;
    if (node >= J.N) return;
    int a = J.rp[node], e1 = J.rp[node + 1];
    float acc[8] = {0.f, 0.f, 0.f, 0.f, 0.f, 0.f, 0.f, 0.f};
    for (int base = a; base < e1; base += TPN) {
        int idx = base + glane;
        int myAdj = (idx < e1) ? J.adj[idx] : 0;
        int cnt = min(TPN, e1 - base);
        int j = 0;
        for (; j + 4 <= cnt; j += 4) {
            int s0 = __shfl(myAdj, j, TPN);
            int s1 = __shfl(myAdj, j + 1, TPN);
            int s2 = __shfl(myAdj, j + 2, TPN);
            int s3 = __shfl(myAdj, j + 3, TPN);
            half8v v0 = *reinterpret_cast<const half8v*>(&J.X[(size_t)s0 * D + glane * 8]);
            half8v v1 = *reinterpret_cast<const half8v*>(&J.X[(size_t)s1 * D + glane * 8]);
            half8v v2 = *reinterpret_cast<const half8v*>(&J.X[(size_t)s2 * D + glane * 8]);
            half8v v3 = *reinterpret_cast<const half8v*>(&J.X[(size_t)s3 * D + glane * 8]);
#pragma unroll
            for (int i = 0; i < 8; ++i)
                acc[i] += (float)v0[i] + (float)v1[i] + (float)v2[i] + (float)v3[i];
        }
        for (; j < cnt; ++j) {
            int s0 = __shfl(myAdj, j, TPN);
            half8v v0 = *reinterpret_cast<const half8v*>(&J.X[(size_t)s0 * D + glane * 8]);
#pragma unroll
            for (int i = 0; i < 8; ++i) acc[i] += (float)v0[i];
        }
    }
    half8v o;
#pragma unroll
    for (int i = 0; i < 8; ++i) o[i] = (_Float16)acc[i];
    *reinterpret_cast<half8v*>(&J.AGG[(size_t)node * D + glane * 8]) = o;
}

// ======================= dual-job MFMA GEMM, 256 threads =======================
// global_load_lds staging, double-buffered row-major LDS [128][64] with granule
// XOR-swizzle; one vmcnt(0)+barrier per chunk; next chunk issued before compute.
// SEGMAX (layer 3): per-wave shfl tree -> LDS cross-wave combine -> non-atomic
// per-block partial [block][2][HID] tagged with graph ids; head2_k reduces.
struct GJob {
    const _Float16* A0; const _Float16* A1; const _Float16* A2;
    const _Float16* W0; const _Float16* W1; const _Float16* W2;
    const float* b0; const float* b1;
    _Float16* O;
    int N; int total; int gb;   // total = NA * (K/64)
    const int* batch;           // SEGMAX only
    const int* starts;          // SEGMAX only
    unsigned* gmU;              // SEGMAX only (fallback sink)
    float* part;                // SEGMAX only: [gb][2][HID]
    int* pgid;                  // SEGMAX only: [gb][2]
};

template <bool RELU, bool SEGMAX>
__global__ __launch_bounds__(256) void gemm2_k(GJob j0, GJob j1, int K, int lg) {
    const bool second = ((int)blockIdx.x >= j0.gb);
    const GJob J = second ? j1 : j0;
    const int bx = blockIdx.x - (second ? j0.gb : 0);
    __shared__ _Float16 Alds[2][128 * 64];   // 2 x 16 KB
    __shared__ _Float16 Wlds[2][128 * 64];   // 2 x 16 KB
    const int tid = threadIdx.x;
    const int lane = tid & 63;
    const int w = tid >> 6;
    const int wr = w & 1, wc = w >> 1;
    const int rowBase = bx * 128;

    f32x16 acc[2][2];
#pragma unroll
    for (int r = 0; r < 2; ++r)
#pragma unroll
        for (int c = 0; c < 2; ++c)
#pragma unroll
            for (int q = 0; q < 16; ++q) acc[r][c][q] = 0.0f;

    const _Float16* Ap[3] = {J.A0, J.A1, J.A2};
    const _Float16* Wp[3] = {J.W0, J.W1, J.W2};

    int srow[4];    // local row this lane loads in call i
    int soff[4];    // byte offset of (swizzled) content granule within row-chunk
    int ldsoff[4];  // wave-uniform LDS byte base of segment i
#pragma unroll
    for (int i = 0; i < 4; ++i) {
        int r_ = (w * 4 + i) * 8 + (lane >> 3);
        srow[i] = r_;
        soff[i] = ((lane & 7) ^ (r_ & 7)) << 4;
        ldsoff[i] = (w * 4 + i) << 10;
    }

    const int total = J.total;
    const int cmask = (1 << lg) - 1;

    auto stage = [&](int c, int buf) {
        const int s = c >> lg;
        const int k0b = (c & cmask) << 7;           // (c&cmask)*64 halves -> bytes
        const char* Ab = (const char*)Ap[s];
        const char* Wb = (const char*)Wp[s];
        char* al = (char*)&Alds[buf][0];
        char* wl = (char*)&Wlds[buf][0];
#pragma unroll
        for (int i = 0; i < 4; ++i) {
            const char* ga = Ab + ((size_t)(rowBase + srow[i]) * K) * 2 + k0b + soff[i];
            const char* gw = Wb + ((size_t)srow[i] * K) * 2 + k0b + soff[i];
            __builtin_amdgcn_global_load_lds(
                (const __attribute__((address_space(1))) void*)ga,
                (__attribute__((address_space(3))) void*)(al + ldsoff[i]), 16, 0, 0);
            __builtin_amdgcn_global_load_lds(
                (const __attribute__((address_space(1))) void*)gw,
                (__attribute__((address_space(3))) void*)(wl + ldsoff[i]), 16, 0, 0);
        }
    };

    stage(0, 0);
    asm volatile("s_waitcnt vmcnt(0)\n\ts_barrier" ::: "memory");

    const int rA0 = wr * 64 + (lane & 31);   // local row for r = 0
    const int cW0 = wc * 64 + (lane & 31);   // local col for cc = 0
    const int ghi = lane >> 5;

    for (int c = 0; c < total; ++c) {
        if (c + 1 < total) stage(c + 1, (c + 1) & 1);
        const _Float16* al = &Alds[c & 1][0];
        const _Float16* wl = &Wlds[c & 1][0];
#pragma unroll
        for (int t = 0; t < 4; ++t) {
            const int g = 2 * t + ghi;
            half8v av[2], wv[2];
#pragma unroll
            for (int r = 0; r < 2; ++r) {
                const int row = rA0 + r * 32;
                av[r] = *reinterpret_cast<const half8v*>(al + ((row * 8 + (g ^ (row & 7))) << 3));
            }
#pragma unroll
            for (int cc = 0; cc < 2; ++cc) {
                const int col = cW0 + cc * 32;
                wv[cc] = *reinterpret_cast<const half8v*>(wl + ((col * 8 + (g ^ (col & 7))) << 3));
            }
#pragma unroll
            for (int r = 0; r < 2; ++r)
#pragma unroll
                for (int cc = 0; cc < 2; ++cc)
                    acc[r][cc] = __builtin_amdgcn_mfma_f32_32x32x16_f16(wv[cc], av[r], acc[r][cc], 0, 0, 0);
        }
        asm volatile("s_waitcnt vmcnt(0)\n\ts_barrier" ::: "memory");
    }

    const int half_ = lane >> 5;   // lanes l and l^32 own the same node
    const int lane31 = lane & 31;

    if constexpr (SEGMAX) {
        __shared__ float smaxS[2][2][HID];   // [slot][wr][f]
        const float NEGINF = -__builtin_huge_valf();
        {
            float* sf = (float*)smaxS;
            sf[tid] = NEGINF;
            sf[tid + 256] = NEGINF;
        }
        const int node0 = rowBase + wr * 64 + lane31;
        const int node1 = node0 + 32;
        const bool ok0 = (node0 < J.N);
        const bool ok1 = (node1 < J.N);
        const int lastn = min(rowBase + 127, J.N - 1);
        const int gfirst = J.batch[rowBase];
        const int glast = J.batch[lastn];
        const int gcnt = glast - gfirst + 1;
        __syncthreads();
        if (gcnt <= 2) {
            const int boundary = (gcnt == 2) ? J.starts[gfirst + 1] : 0x7FFFFFFF;
            for (int s = 0; s < gcnt; ++s) {
                const bool in0 = ok0 && ((node0 >= boundary) == (s == 1));
                const bool in1 = ok1 && ((node1 >= boundary) == (s == 1));
#pragma unroll
                for (int cc = 0; cc < 2; ++cc)
#pragma unroll
                for (int g = 0; g < 4; ++g) {
                    const int f = wc * 64 + cc * 32 + g * 8 + 4 * half_;
                    float4 bv = *reinterpret_cast<const float4*>(&J.b0[f]);
                    if (J.b1) {
                        float4 b2v = *reinterpret_cast<const float4*>(&J.b1[f]);
                        bv.x += b2v.x; bv.y += b2v.y; bv.z += b2v.z; bv.w += b2v.w;
                    }
#pragma unroll
                    for (int i = 0; i < 4; ++i) {
                        float bb_ = ((const float*)&bv)[i];
                        float v0 = in0 ? (acc[0][cc][g * 4 + i] + bb_) : NEGINF;
                        float v1 = in1 ? (acc[1][cc][g * 4 + i] + bb_) : NEGINF;
                        float vm = fmaxf(v0, v1);
#pragma unroll
                        for (int off = 1; off < 32; off <<= 1)
                            vm = fmaxf(vm, __shfl_xor(vm, off, 32));
                        if (lane31 == 0) smaxS[s][wr][f + i] = vm;
                    }
                }
            }
        } else {
            // astronomically rare (>2 graphs in one 128-row block): direct atomics
#pragma unroll
            for (int r = 0; r < 2; ++r) {
                const int node = rowBase + wr * 64 + r * 32 + lane31;
                if (node >= J.N) continue;
                const int gid = J.batch[node];
                unsigned* gbase = J.gmU + (size_t)gid * HID;
#pragma unroll
                for (int cc = 0; cc < 2; ++cc)
#pragma unroll
                for (int g = 0; g < 4; ++g) {
                    const int f = wc * 64 + cc * 32 + g * 8 + 4 * half_;
                    float4 bv = *reinterpret_cast<const float4*>(&J.b0[f]);
                    if (J.b1) {
                        float4 b2v = *reinterpret_cast<const float4*>(&J.b1[f]);
                        bv.x += b2v.x; bv.y += b2v.y; bv.z += b2v.z; bv.w += b2v.w;
                    }
#pragma unroll
                    for (int i = 0; i < 4; ++i) {
                        float v = acc[r][cc][g * 4 + i] + ((const float*)&bv)[i];
                        atomicMax(&gbase[f + i], encf(v));
                    }
                }
            }
        }
        __syncthreads();
        if (tid < 128) {
#pragma unroll
            for (int s = 0; s < 2; ++s) {
                float m = fmaxf(smaxS[s][0][tid], smaxS[s][1][tid]);
                J.part[((size_t)bx * 2 + s) * HID + tid] = m;
            }
        }
        if (tid < 2) J.pgid[bx * 2 + tid] = (gcnt <= 2 && tid < gcnt) ? gfirst + tid : -1;
        return;
    }

    // ---- epilogue: lane-pair merged 16 B stores ----
#pragma unroll
    for (int r = 0; r < 2; ++r) {
        int node = rowBase + (wr * 2 + r) * 32 + lane31;
        bool ok = (node < J.N);
        _Float16* orow = J.O + (size_t)node * HID;
#pragma unroll
        for (int cc = 0; cc < 2; ++cc) {
            int fbase = wc * 64 + cc * 32;
#pragma unroll
            for (int g = 0; g < 4; ++g) {
                int fmine = fbase + g * 8 + 4 * half_;
                float4 bv = *reinterpret_cast<const float4*>(&J.b0[fmine]);
                if (J.b1) {
                    float4 b2v = *reinterpret_cast<const float4*>(&J.b1[fmine]);
                    bv.x += b2v.x; bv.y += b2v.y; bv.z += b2v.z; bv.w += b2v.w;
                }
                union { half4v h; int i[2]; } m, p;
#pragma unroll
                for (int i = 0; i < 4; ++i) {
                    float v = acc[r][cc][g * 4 + i] + ((const float*)&bv)[i];
                    if (RELU) v = fmaxf(v, 0.f);
                    m.h[i] = (_Float16)v;
                }
                p.i[0] = __shfl_xor(m.i[0], 32);
                p.i[1] = __shfl_xor(m.i[1], 32);
                half4v lo = half_ ? p.h : m.h;
                half4v hi = half_ ? m.h : p.h;
                half8v outv;
#pragma unroll
                for (int i = 0; i < 4; ++i) { outv[i] = lo[i]; outv[4 + i] = hi[i]; }
                if (ok && ((g & 1) == half_))
                    *reinterpret_cast<half8v*>(&orow[fbase + g * 8]) = outv;
            }
        }
    }
}

// ---- fused readout: partial-max scan + per-graph MLP heads, grid (G), 128 thr ----
__global__ __launch_bounds__(128) void head2_k(
    const float* __restrict__ pP, const int* __restrict__ gP,
    const int* __restrict__ stP, const unsigned* __restrict__ gmP,
    const float* __restrict__ pR, const int* __restrict__ gR,
    const int* __restrict__ stR, const unsigned* __restrict__ gmR,
    const float* __restrict__ W1, const float* __restrict__ b1,
    const float* __restrict__ W2, const float* __restrict__ b2,
    const float* __restrict__ oW, const float* __restrict__ ob,
    float* __restrict__ out) {
    const int g = blockIdx.x;
    const int f = threadIdx.x;
    __shared__ float red[128];
    float vv[2];
    for (int t = 0; t < 2; ++t) {
        const float* part   = t ? pR : pP;
        const int* pgid     = t ? gR : gP;
        const int* starts   = t ? stR : stP;
        const unsigned* gmU = t ? gmR : gmP;
        int s0 = starts[g], s1 = starts[g + 1];
        float m = -__builtin_huge_valf();
        if (s0 < s1) {
            int b0 = s0 >> 7, b1_ = (s1 - 1) >> 7;
            for (int b = b0; b <= b1_; ++b) {
#pragma unroll
                for (int s = 0; s < 2; ++s) {
                    if (pgid[b * 2 + s] == g)
                        m = fmaxf(m, part[((size_t)b * 2 + s) * HID + f]);
                }
            }
        }
        unsigned u = gmU[(size_t)g * HID + f];
        if (u) m = fmaxf(m, decf(u));   // rare fallback contributions
        float o = 0.f;
        if (f == 0) o = b2[t];
#pragma unroll
        for (int j = 0; j < 5; ++j) {
            red[f] = m * W1[t * HID * 5 + f * 5 + j];
            __syncthreads();
            for (int off = 64; off > 0; off >>= 1) {
                if (f < off) red[f] += red[f + off];
                __syncthreads();
            }
            if (f == 0) o = fmaf(fmaxf(red[0] + b1[t * 5 + j], 0.f), W2[t * 5 + j], o);
            __syncthreads();
        }
        vv[t] = o;
    }
    if (f == 0) out[g] = vv[0] * oW[0] + vv[1] * oW[1] + ob[0];
}

extern "C" void kernel_launch(void* const* d_in, const int* in_sizes, int n_in,
                              void* d_out, int out_size, void* d_ws, size_t ws_size,
                              hipStream_t stream) {
    const float* x_pe    = (const float*)d_in[0];
    const float* x_r     = (const float*)d_in[1];
    const int* ei_per    = (const int*)d_in[2];
    const int* ei_rpe    = (const int*)d_in[3];
    const int* ei_rr     = (const int*)d_in[4];
    const int* batch_pe  = (const int*)d_in[5];
    const int* batch_r   = (const int*)d_in[6];
    const float* Wrel1   = (const float*)d_in[7];
    const float* brel1   = (const float*)d_in[8];
    const float* Wroot1  = (const float*)d_in[9];
    const float* Wrel23  = (const float*)d_in[10];
    const float* brel23  = (const float*)d_in[11];
    const float* Wroot23 = (const float*)d_in[12];
    const float* mlp_W1  = (const float*)d_in[13];
    const float* mlp_b1  = (const float*)d_in[14];
    const float* mlp_W2  = (const float*)d_in[15];
    const float* mlp_b2  = (const float*)d_in[16];
    const float* out_W   = (const float*)d_in[17];
    const float* out_b   = (const float*)d_in[18];
    float* out = (float*)d_out;

    const int N_PE = in_sizes[0] / DIN;
    const int N_R  = in_sizes[1] / DIN;
    const int E    = in_sizes[2] / 2;
    const int G    = out_size;
    const int NMAX = (N_PE > N_R) ? N_PE : N_R;
    const size_t SZM = (size_t)NMAX * HID;

    // ---- workspace layout ----
    _Float16* H1 = (_Float16*)d_ws;
    _Float16* H2 = H1 + SZM;
    _Float16* H3 = H2 + SZM;
    _Float16* H4 = H3 + SZM;
    _Float16* H5 = H4 + SZM;
    _Float16* xh_pe = H5 + SZM;
    _Float16* xh_r  = xh_pe + (size_t)N_PE * DIN;
    _Float16* wt_rel1    = xh_r + (size_t)N_R * DIN;   // 3 x 128 x 64
    _Float16* wt_root1pe = wt_rel1 + 3 * DIN * HID;    // 128 x 64
    _Float16* wt_wsum1   = wt_root1pe + DIN * HID;     // 128 x 64
    _Float16* wt_rel23   = wt_wsum1 + DIN * HID;       // 6 x 128 x 128
    _Float16* wt_root_l2 = wt_rel23 + 6 * HID * HID;   // 128 x 128
    _Float16* wt_root_l3 = wt_root_l2 + HID * HID;     // 128 x 128
    _Float16* wt_wsum2   = wt_root_l3 + HID * HID;     // 128 x 128
    _Float16* wt_wsum3   = wt_wsum2 + HID * HID;       // 128 x 128
    unsigned* gmU_pe = (unsigned*)(wt_wsum3 + HID * HID);
    unsigned* gmU_r  = gmU_pe + G * HID;
    int* bktCnt = (int*)(gmU_r + G * HID);       // 3 * NBKMAX
    int* starts_pe = bktCnt + 3 * NBKMAX;
    int* starts_r  = starts_pe + (G + 1);
    int* bb     = starts_r + (G + 1);            // 3 * (NBKMAX+1)
    int* gcur   = bb + 3 * (NBKMAX + 1);         // 3 * NBKMAX
    int* csr    = gcur + 3 * NBKMAX;
    const size_t relstride = (size_t)(NMAX + 1) + 2 * (size_t)E + 16;

    int* rp[3]; int* adjp[3]; unsigned* tmp[3];
    const int Nds[3] = {N_R, N_PE, N_R};
    for (int r = 0; r < 3; ++r) {
        int* rowptr = csr + (size_t)r * relstride;
        rp[r] = rowptr;
        adjp[r] = rowptr + (Nds[r] + 1);
        tmp[r] = (unsigned*)(adjp[r] + E);
    }

    const int gpe = (N_PE + 127) / 128, grr = (N_R + 127) / 128;
    const int eb = (E + EPB - 1) / EPB;

    // ---- segmax partial buffers carved from tmp[0] scratch (free during layers) ----
    float* part_pe = (float*)tmp[0];
    float* part_r  = part_pe + (size_t)gpe * 2 * HID;
    int*   pgid_pe = (int*)(part_r + (size_t)grr * 2 * HID);
    int*   pgid_r  = pgid_pe + gpe * 2;

    // ---- zero gmU + bucket counters (contiguous) ----
    hipMemsetAsync(gmU_pe, 0, (2 * (size_t)G * HID + 3 * NBKMAX) * sizeof(int), stream);
    // ---- input conversion ----
    {
        int n40 = N_PE * DIN / 4, n41 = N_R * DIN / 4;
        int nmax = n40 > n41 ? n40 : n41;
        dim3 g((nmax + 255) / 256, 2);
        conv_x2_k<<<g, 256, 0, stream>>>(x_pe, xh_pe, n40, x_r, xh_r, n41);
    }
    // ---- prep: weight conversion + bucket hist + segment bounds, 1 launch ----
    {
        CW c0{Wrel1, nullptr, wt_rel1, DIN, 3 * DIN * HID};
        CW c1{Wroot1 + 1 * DIN * HID, nullptr, wt_root1pe, DIN, DIN * HID};
        CW c2{Wroot1, Wroot1 + 2 * DIN * HID, wt_wsum1, DIN, DIN * HID};
        CW c3{Wrel23, nullptr, wt_rel23, HID, 6 * HID * HID};
        CW c4{Wroot23 + 1 * HID * HID, nullptr, wt_root_l2, HID, HID * HID};
        CW c5{Wroot23 + 4 * HID * HID, nullptr, wt_root_l3, HID, HID * HID};
        CW c6{Wroot23, Wroot23 + 2 * HID * HID, wt_wsum2, HID, HID * HID};
        CW c7{Wroot23 + 3 * HID * HID, Wroot23 + 5 * HID * HID, wt_wsum3, HID, HID * HID};
        int gx = (6 * HID * HID + 255) / 256;
        if (eb > gx) gx = eb;
        dim3 g(gx, 12);
        prep_k<<<g, 256, 0, stream>>>(c0, c1, c2, c3, c4, c5, c6, c7,
                                      ei_per, ei_rpe, ei_rr, E,
                                      bktCnt, bktCnt + NBKMAX, bktCnt + 2 * NBKMAX,
                                      batch_pe, N_PE, starts_pe,
                                      batch_r, N_R, starts_r, G);
    }
    // ---- CSR build ----
    {
        bscan_k<<<1, 256, 0, stream>>>(
            bktCnt, bb, gcur, rp[0], Nds[0],
            bktCnt + NBKMAX, bb + (NBKMAX + 1), gcur + NBKMAX, rp[1], Nds[1],
            bktCnt + 2 * NBKMAX, bb + 2 * (NBKMAX + 1), gcur + 2 * NBKMAX, rp[2], Nds[2], E);
        dim3 gh(eb, 3);
        bin_k<<<gh, 256, 0, stream>>>(ei_per, ei_rpe, ei_rr, E,
                                      gcur, gcur + NBKMAX, gcur + 2 * NBKMAX,
                                      tmp[0], tmp[1], tmp[2]);
        dim3 gc(NBKMAX, 3);
        bcsr_k<<<gc, 256, 0, stream>>>(tmp[0], tmp[1], tmp[2],
                                       bb, bb + (NBKMAX + 1), bb + 2 * (NBKMAX + 1),
                                       rp[0], rp[1], rp[2],
                                       adjp[0], adjp[1], adjp[2],
                                       Nds[0], Nds[1], Nds[2]);
    }

    // ---------- layer 1 (K = 64) ----------
    {
        AJob a0{xh_r, rp[1], adjp[1], H1, N_PE, (N_PE + 31) / 32};
        AJob a1{xh_pe, rp[0], adjp[0], H2, N_R, (N_R + 31) / 32};
        AJob a2{xh_r, rp[2], adjp[2], H3, N_R, (N_R + 31) / 32};
        gather3_k<DIN><<<a0.gb + a1.gb + a2.gb, 256, 0, stream>>>(a0, a1, a2);
        GJob jp{H1, xh_pe, nullptr,
                wt_rel1 + 1 * DIN * HID, wt_root1pe, nullptr,
                brel1 + HID, nullptr, H4, N_PE, 2, gpe,
                nullptr, nullptr, nullptr, nullptr, nullptr};
        GJob jr{H2, H3, xh_r,
                wt_rel1, wt_rel1 + 2 * DIN * HID, wt_wsum1,
                brel1, brel1 + 2 * HID, H5, N_R, 3, grr,
                nullptr, nullptr, nullptr, nullptr, nullptr};
        gemm2_k<true, false><<<gpe + grr, 256, 0, stream>>>(jp, jr, DIN, 0);
    }
    // ---------- layer 2 (K = 128) ----------
    {
        AJob a0{H5, rp[1], adjp[1], H1, N_PE, (N_PE + 15) / 16};
        AJob a1{H4, rp[0], adjp[0], H2, N_R, (N_R + 15) / 16};
        AJob a2{H5, rp[2], adjp[2], H3, N_R, (N_R + 15) / 16};
        gather3_k<HID><<<a0.gb + a1.gb + a2.gb, 256, 0, stream>>>(a0, a1, a2);
        GJob jp{H1, H4, nullptr,
                wt_rel23 + 1 * HID * HID, wt_root_l2, nullptr,
                brel23 + HID, nullptr, H1, N_PE, 2 * 2, gpe,
                nullptr, nullptr, nullptr, nullptr, nullptr};
        GJob jr{H2, H3, H5,
                wt_rel23, wt_rel23 + 2 * HID * HID, wt_wsum2,
                brel23, brel23 + 2 * HID, H2, N_R, 3 * 2, grr,
                nullptr, nullptr, nullptr, nullptr, nullptr};
        gemm2_k<true, false><<<gpe + grr, 256, 0, stream>>>(jp, jr, HID, 1);
    }
    // ---------- layer 3 (K = 128), no ReLU, fused segment-max ----------
    {
        AJob a0{H2, rp[1], adjp[1], H3, N_PE, (N_PE + 15) / 16};
        AJob a1{H1, rp[0], adjp[0], H4, N_R, (N_R + 15) / 16};
        AJob a2{H2, rp[2], adjp[2], H5, N_R, (N_R + 15) / 16};
        gather3_k<HID><<<a0.gb + a1.gb + a2.gb, 256, 0, stream>>>(a0, a1, a2);
        GJob jp{H3, H1, nullptr,
                wt_rel23 + 4 * HID * HID, wt_root_l3, nullptr,
                brel23 + 4 * HID, nullptr, nullptr, N_PE, 2 * 2, gpe,
                batch_pe, starts_pe, gmU_pe, part_pe, pgid_pe};
        GJob jr{H4, H5, H2,
                wt_rel23 + 3 * HID * HID, wt_rel23 + 5 * HID * HID, wt_wsum3,
                brel23 + 3 * HID, brel23 + 5 * HID, nullptr, N_R, 3 * 2, grr,
                batch_r, starts_r, gmU_r, part_r, pgid_r};
        gemm2_k<false, true><<<gpe + grr, 256, 0, stream>>>(jp, jr, HID, 1);
    }

    // ---------- fused readout: partial reduce + MLP heads, one launch ----------
    head2_k<<<G, 128, 0, stream>>>(part_pe, pgid_pe, starts_pe, gmU_pe,
                                   part_r, pgid_r, starts_r, gmU_r,
                                   mlp_W1, mlp_b1, mlp_W2, mlp_b2, out_W, out_b, out);
}